// Round 4
// baseline (435.592 us; speedup 1.0000x reference)
//
#include <hip/hip_runtime.h>
#include <stdint.h>
#include <stddef.h>

#define B_ 8
#define D_ 128
#define T_ 32768
#define C_ 64
#define NCH_ 128      // t-chunks per batch in k1; Tc = 256 -> 1024 blocks = 4/CU

typedef __bf16 bf16;
typedef __bf16 bf16x4 __attribute__((ext_vector_type(4)));
typedef __bf16 bf16x8 __attribute__((ext_vector_type(8)));
typedef float f32x4 __attribute__((ext_vector_type(4)));
typedef float f32x16 __attribute__((ext_vector_type(16)));

__device__ __forceinline__ f32x16 zero16() {
  f32x16 z;
#pragma unroll
  for (int i = 0; i < 16; ++i) z[i] = 0.f;
  return z;
}

// ---------------------------------------------------------------------------
// K0: zero helper (split-K path only needs r zeroed; fallback zeroes G too)
// ---------------------------------------------------------------------------
__global__ __launch_bounds__(256) void k0_zero(float* __restrict__ p, int n)
{
  int i = blockIdx.x * 256 + threadIdx.x;
  if (i < n) p[i] = 0.f;
}

// ---------------------------------------------------------------------------
// K1: Gram partials Gpart[blk] = x1_chunk x1_chunk^T via LDS-staged tiles.
//     1024 gram blocks (4/CU, 16 waves/CU) so HBM latency is TLP-hidden;
//     register prefetch (stage s+1 loads issue before stage-s MFMAs) adds ILP.
//     Each block owns a 64 KB fp32 partial slot (k2 reduces). Row-sums r via
//     cheap atomics (65K ops). 96 extra blocks fold weights:
//     wk'=we@wk(+bk'), wv'=wf@wv(+bv'), wo -> bf16.
//     Fallback (gpart==nullptr): atomicAdd-into-G path.
// ---------------------------------------------------------------------------
__global__ __launch_bounds__(256, 4) void k1_gram(
    const float* __restrict__ x1,
    const float* __restrict__ we, const float* __restrict__ wk,
    const float* __restrict__ bk, const float* __restrict__ be,
    const float* __restrict__ wf, const float* __restrict__ wv,
    const float* __restrict__ bv, const float* __restrict__ bfv,
    const float* __restrict__ wo,
    float* __restrict__ G, float* __restrict__ r,
    float* __restrict__ wkp, float* __restrict__ wvp,
    float* __restrict__ bkp, float* __restrict__ bvp,
    bf16* __restrict__ wobf,
    float* __restrict__ gpart)
{
  const int blk = blockIdx.x;
  const int tid = threadIdx.x;
  const int ngram = B_ * NCH_;   // 1024

  if (blk >= ngram) {
    const int wb = blk - ngram;  // 0..95
    if (wb < 64) {               // folded weights
      const float* wa  = (wb < 32) ? we : wf;
      const float* wb2 = (wb < 32) ? wk : wv;
      float* outw      = (wb < 32) ? wkp : wvp;
      const int idx = (wb & 31) * 256 + tid;   // 0..8191
      const int o = idx >> 7, d = idx & 127;
      float s = 0.f;
      for (int c = 0; c < 64; ++c) s += wa[o * 64 + c] * wb2[c * 128 + d];
      outw[idx] = s;
      if (tid < 64) {
        if (wb == 0) {
          float t = 0.f;
          for (int c = 0; c < 64; ++c) t += we[tid * 64 + c] * bk[c];
          bkp[tid] = t + be[tid];
        } else if (wb == 32) {
          float t = 0.f;
          for (int c = 0; c < 64; ++c) t += wf[tid * 64 + c] * bv[c];
          bvp[tid] = t + bfv[tid];
        }
      }
    } else {                     // wo -> bf16 (8192 elements over 32 blocks)
      const int idx = (wb - 64) * 256 + tid;
      wobf[idx] = (bf16)wo[idx];
    }
    return;
  }

  __shared__ bf16 x_s[128 * 72];   // [row][kcol], pad 64->72 (16B-aligned rows)

  const int b  = blk >> 7;                   // NCH_ = 128
  const int ch = blk & (NCH_ - 1);
  const int t0 = ch * (T_ / NCH_);           // Tc = 256
  const int wave = tid >> 6, lane = tid & 63;
  const int lrow = lane & 31, lk = lane >> 5;
  const int qa = wave >> 1, qb = wave & 1;   // wave owns 64x64 quadrant

  const float* xb = x1 + (size_t)b * D_ * T_;

  f32x16 acc00 = zero16(), acc01 = zero16(), acc10 = zero16(), acc11 = zero16();
  float rsum = 0.f;

  const int scol = (tid & 15) * 4;           // staging col for this thread
  const int srow0 = tid >> 4;                // staging row base (0..15)

  const bf16* A0  = &x_s[(64 * qa + lrow) * 72 + 8 * lk];
  const bf16* A1  = A0 + 32 * 72;
  const bf16* Bb0 = &x_s[(64 * qb + lrow) * 72 + 8 * lk];
  const bf16* Bb1 = Bb0 + 32 * 72;

  // prefetch stage 0 into registers
  f32x4 pre[8];
#pragma unroll
  for (int it = 0; it < 8; ++it) {
    const int row = it * 16 + srow0;
    pre[it] = *(const f32x4*)(xb + (size_t)row * T_ + t0 + scol);
  }

  for (int s = 0; s < 4; ++s) {              // 4 stages of 64 t-cols
    if (s) __syncthreads();                  // prev-stage reads done before overwrite
#pragma unroll
    for (int it = 0; it < 8; ++it) {
      const int row = it * 16 + srow0;
      bf16x4 h;
#pragma unroll
      for (int j = 0; j < 4; ++j) h[j] = (bf16)pre[it][j];
      *(bf16x4*)&x_s[row * 72 + scol] = h;
    }
    __syncthreads();
    if (s < 3) {                             // issue next-stage loads EARLY
      const int tb = t0 + (s + 1) * 64;
#pragma unroll
      for (int it = 0; it < 8; ++it) {
        const int row = it * 16 + srow0;
        pre[it] = *(const f32x4*)(xb + (size_t)row * T_ + tb + scol);
      }
    }
#pragma unroll
    for (int k = 0; k < 4; ++k) {
      bf16x8 fa0 = *(const bf16x8*)(A0 + 16 * k);
      bf16x8 fa1 = *(const bf16x8*)(A1 + 16 * k);
      bf16x8 fb0 = *(const bf16x8*)(Bb0 + 16 * k);
      bf16x8 fb1 = *(const bf16x8*)(Bb1 + 16 * k);
      bf16x8 own = qb ? fa1 : fa0;           // wave w sums rows 32w..32w+31
#pragma unroll
      for (int j = 0; j < 8; ++j) rsum += (float)own[j];
      acc00 = __builtin_amdgcn_mfma_f32_32x32x16_bf16(fa0, fb0, acc00, 0, 0, 0);
      acc01 = __builtin_amdgcn_mfma_f32_32x32x16_bf16(fa0, fb1, acc01, 0, 0, 0);
      acc10 = __builtin_amdgcn_mfma_f32_32x32x16_bf16(fa1, fb0, acc10, 0, 0, 0);
      acc11 = __builtin_amdgcn_mfma_f32_32x32x16_bf16(fa1, fb1, acc11, 0, 0, 0);
    }
  }

  if (gpart) {
    // split-K partial: this block owns its own 64 KB slot -> plain stores
    float* gp = gpart + (size_t)blk * 16384;
#pragma unroll
    for (int rr = 0; rr < 16; ++rr) {
      const int rloc = (rr & 3) + 8 * (rr >> 2) + 4 * lk;   // C/D row map
      const int r0 = 64 * qa + rloc, r1 = 64 * qa + 32 + rloc;
      const int c0 = 64 * qb + lrow, c1 = 64 * qb + 32 + lrow;
      gp[r0 * 128 + c0] = acc00[rr];
      gp[r0 * 128 + c1] = acc01[rr];
      gp[r1 * 128 + c0] = acc10[rr];
      gp[r1 * 128 + c1] = acc11[rr];
    }
  } else {
    float* gb = G + (size_t)b * 16384;
#pragma unroll
    for (int rr = 0; rr < 16; ++rr) {
      const int rloc = (rr & 3) + 8 * (rr >> 2) + 4 * lk;
      const int r0 = 64 * qa + rloc, r1 = 64 * qa + 32 + rloc;
      const int c0 = 64 * qb + lrow, c1 = 64 * qb + 32 + lrow;
      atomicAdd(&gb[r0 * 128 + c0], acc00[rr]);
      atomicAdd(&gb[r0 * 128 + c1], acc01[rr]);
      atomicAdd(&gb[r1 * 128 + c0], acc10[rr]);
      atomicAdd(&gb[r1 * 128 + c1], acc11[rr]);
    }
  }
  float rtot = rsum + __shfl_xor(rsum, 32, 64);
  if (lk == 0) atomicAdd(&r[b * 128 + 32 * wave + lrow], rtot);
}

// ---------------------------------------------------------------------------
// K2: G[b] = sum over NCH_ partials. f32x4 per thread, fully coalesced.
// ---------------------------------------------------------------------------
__global__ __launch_bounds__(256) void k2_reduce(
    const float* __restrict__ gpart, float* __restrict__ G)
{
  const int g4 = blockIdx.x * 256 + threadIdx.x;  // 0..32767 (4 floats each)
  const int b = g4 >> 12;                          // 4096 f32x4 per batch
  const int e4 = g4 & 4095;
  const f32x4* p = (const f32x4*)(gpart + ((size_t)b * NCH_) * 16384) + e4;
  f32x4 s = {0.f, 0.f, 0.f, 0.f};
#pragma unroll 8
  for (int ch = 0; ch < NCH_; ++ch) s += p[(size_t)ch * 4096];
  *((f32x4*)G + g4) = s;
}

// ---------------------------------------------------------------------------
// K3: per (b, c): S[c,:] = wq_c G wk'^T + exact bias terms (via r),
//     P = softmax(S/8), att_w[c,:] = P @ wv' (bf16), att_b[c] = P @ bv'
// ---------------------------------------------------------------------------
__global__ __launch_bounds__(128) void k3_softmax(
    const float* __restrict__ wq, const float* __restrict__ bq,
    const float* __restrict__ G, const float* __restrict__ r,
    const float* __restrict__ wkp, const float* __restrict__ wvp,
    const float* __restrict__ bkp, const float* __restrict__ bvp,
    bf16* __restrict__ attw, float* __restrict__ attb)
{
  const int b = blockIdx.x >> 6, c = blockIdx.x & 63;
  const int tid = threadIdx.x;
  __shared__ float sM[128], sR[128], sQ[128], sP[64];
  __shared__ float sRed;

  const float* Gb = G + (size_t)b * 16384;
  const float* wqc = wq + c * 128;

  const float rv = r[b * 128 + tid];
  sR[tid] = rv;
  float m = 0.f;
  for (int j = 0; j < 128; ++j) m += wqc[j] * Gb[j * 128 + tid];
  sM[tid] = m;
  sQ[tid] = wqc[tid] * rv;
  __syncthreads();

  if (tid < 64) {
    float q2 = sQ[tid] + sQ[tid + 64];
#pragma unroll
    for (int off = 32; off; off >>= 1) q2 += __shfl_xor(q2, off, 64);
    if (tid == 0) sRed = q2;
  }
  __syncthreads();
  const float qr = sRed;
  const float bqc = bq[c];

  if (tid < 64) {
    const int k = tid;
    float s = 0.f, wkr = 0.f;
    for (int i = 0; i < 128; ++i) {
      const float w = wkp[k * 128 + i];
      s += sM[i] * w;
      wkr += sR[i] * w;
    }
    const float bk2 = bkp[k];
    float logit = (s + bqc * wkr + bk2 * qr + (float)T_ * bqc * bk2) * 0.125f;
    float mx = logit;
#pragma unroll
    for (int off = 32; off; off >>= 1) mx = fmaxf(mx, __shfl_xor(mx, off, 64));
    const float e = __expf(logit - mx);
    float sum = e;
#pragma unroll
    for (int off = 32; off; off >>= 1) sum += __shfl_xor(sum, off, 64);
    sP[k] = e / sum;
  }
  __syncthreads();

  {
    float aw = 0.f;
    for (int k = 0; k < 64; ++k) aw += sP[k] * wvp[k * 128 + tid];
    attw[((size_t)b * 64 + c) * 128 + tid] = (bf16)aw;
  }
  if (tid < 64) {
    float pb = sP[tid] * bvp[tid];
#pragma unroll
    for (int off = 32; off; off >>= 1) pb += __shfl_xor(pb, off, 64);
    if (tid == 0) attb[b * 64 + c] = pb;
  }
}

// ---------------------------------------------------------------------------
// K4: fused output, barrier-free main path. Per (b, 128-wide t-tile):
//   stage1 B-frags read DIRECTLY from global x1 (coalesced dword loads),
//   M1 = relu(attw@x + ab) -> small [t][c] LDS (within-lane rows only ->
//   no barrier), stage2 out = wobf@m1 + bo, masked fp32 store.
// ---------------------------------------------------------------------------
__global__ __launch_bounds__(256, 4) void k4_out(
    const float* __restrict__ x1, const float* __restrict__ mask,
    const bf16* __restrict__ wobf, const float* __restrict__ bo,
    const bf16* __restrict__ attw, const float* __restrict__ attb,
    float* __restrict__ out)
{
  __shared__ bf16 m1[128 * 72];   // [t][c], pad 64->72
  __shared__ float bo_s[128];
  __shared__ float ab_s[64];

  const int b = blockIdx.x >> 8;           // 256 tiles per batch
  const int t0 = (blockIdx.x & 255) << 7;
  const int tid = threadIdx.x;
  const int wave = tid >> 6, lane = tid & 63;
  const int lrow = lane & 31, lk = lane >> 5;
  const int tcol = 32 * wave + lrow;

  if (tid < 128) bo_s[tid] = bo[tid];
  if (tid < 64) ab_s[tid] = attb[b * 64 + tid];
  __syncthreads();                          // only barrier (tiny staging)

  const float* xc = x1 + (size_t)b * D_ * T_ + t0 + tcol;   // column base
  const bf16* awb = attw + (size_t)b * 8192;

  // ---- stage 1: M1[c][t] = attw[c][d] * x[d][t]
  f32x16 p0 = zero16(), p1 = zero16();
#pragma unroll
  for (int k0 = 0; k0 < 8; ++k0) {
    bf16x8 a0 = *(const bf16x8*)(awb + (size_t)lrow * 128 + 16 * k0 + 8 * lk);
    bf16x8 a1 = *(const bf16x8*)(awb + (size_t)(32 + lrow) * 128 + 16 * k0 + 8 * lk);
    bf16x8 bx;
#pragma unroll
    for (int j = 0; j < 8; ++j)
      bx[j] = (bf16)xc[(size_t)(16 * k0 + 8 * lk + j) * T_];
    p0 = __builtin_amdgcn_mfma_f32_32x32x16_bf16(a0, bx, p0, 0, 0, 0);
    p1 = __builtin_amdgcn_mfma_f32_32x32x16_bf16(a1, bx, p1, 0, 0, 0);
  }
  bf16* mrow = &m1[tcol * 72];              // this lane's own t-row
#pragma unroll
  for (int rr = 0; rr < 16; ++rr) {
    const int row = (rr & 3) + 8 * (rr >> 2) + 4 * lk;
    mrow[row]      = (bf16)fmaxf(p0[rr] + ab_s[row], 0.f);
    mrow[32 + row] = (bf16)fmaxf(p1[rr] + ab_s[32 + row], 0.f);
  }

  // ---- stage 2: out[d][t] = wobf[d][c] * m1[c][t] (own row, no barrier)
  f32x16 q0 = zero16(), q1 = zero16(), q2 = zero16(), q3 = zero16();
#pragma unroll
  for (int k0 = 0; k0 < 4; ++k0) {
    bf16x8 bm = *(const bf16x8*)(mrow + 16 * k0 + 8 * lk);
    bf16x8 w0 = *(const bf16x8*)(wobf + (size_t)(lrow) * 64 + 16 * k0 + 8 * lk);
    bf16x8 w1 = *(const bf16x8*)(wobf + (size_t)(32 + lrow) * 64 + 16 * k0 + 8 * lk);
    bf16x8 w2 = *(const bf16x8*)(wobf + (size_t)(64 + lrow) * 64 + 16 * k0 + 8 * lk);
    bf16x8 w3 = *(const bf16x8*)(wobf + (size_t)(96 + lrow) * 64 + 16 * k0 + 8 * lk);
    q0 = __builtin_amdgcn_mfma_f32_32x32x16_bf16(w0, bm, q0, 0, 0, 0);
    q1 = __builtin_amdgcn_mfma_f32_32x32x16_bf16(w1, bm, q1, 0, 0, 0);
    q2 = __builtin_amdgcn_mfma_f32_32x32x16_bf16(w2, bm, q2, 0, 0, 0);
    q3 = __builtin_amdgcn_mfma_f32_32x32x16_bf16(w3, bm, q3, 0, 0, 0);
  }

  const float mv = mask[(size_t)b * T_ + t0 + tcol];
  float* ob = out + (size_t)b * D_ * T_ + t0 + tcol;
#pragma unroll
  for (int rr = 0; rr < 16; ++rr) {
    const int row = (rr & 3) + 8 * (rr >> 2) + 4 * lk;
    ob[(size_t)(row) * T_]      = (q0[rr] + bo_s[row]) * mv;
    ob[(size_t)(32 + row) * T_] = (q1[rr] + bo_s[32 + row]) * mv;
    ob[(size_t)(64 + row) * T_] = (q2[rr] + bo_s[64 + row]) * mv;
    ob[(size_t)(96 + row) * T_] = (q3[rr] + bo_s[96 + row]) * mv;
  }
}

// ---------------------------------------------------------------------------
// Workspace: small buffers ~0.75 MB, Gpart 1024*64KB = 67 MB (split-K).
// Fallback to atomic path if ws too small.
// ---------------------------------------------------------------------------
extern "C" void kernel_launch(void* const* d_in, const int* in_sizes, int n_in,
                              void* d_out, int out_size, void* d_ws, size_t ws_size,
                              hipStream_t stream)
{
  const float* x1   = (const float*)d_in[0];
  // d_in[1] = x2 (unused in encoder stage)
  const float* mask = (const float*)d_in[2];
  const float* wq   = (const float*)d_in[3];
  const float* bq   = (const float*)d_in[4];
  const float* wk   = (const float*)d_in[5];
  const float* bk   = (const float*)d_in[6];
  const float* wv   = (const float*)d_in[7];
  const float* bv   = (const float*)d_in[8];
  const float* we   = (const float*)d_in[9];
  const float* be   = (const float*)d_in[10];
  const float* wf   = (const float*)d_in[11];
  const float* bfv  = (const float*)d_in[12];
  const float* wo   = (const float*)d_in[13];
  const float* bo   = (const float*)d_in[14];
  float* out = (float*)d_out;

  char* base = (char*)d_ws;
  size_t off = 0;
  float* G    = (float*)(base + off); off += (size_t)B_ * 16384 * 4;
  float* r    = (float*)(base + off); off += (size_t)B_ * 128 * 4;
  float* wkp  = (float*)(base + off); off += 8192 * 4;
  float* wvp  = (float*)(base + off); off += 8192 * 4;
  float* bkp  = (float*)(base + off); off += 64 * 4;
  float* bvp  = (float*)(base + off); off += 64 * 4;
  float* attb = (float*)(base + off); off += (size_t)B_ * 64 * 4;
  bf16* attw  = (bf16*)(base + off);  off += (size_t)B_ * 64 * 128 * 2;
  bf16* wobf  = (bf16*)(base + off);  off += 8192 * 2;
  off = (off + 15) & ~(size_t)15;
  float* gpart = (float*)(base + off);
  const size_t need = off + (size_t)B_ * NCH_ * 16384 * 4;
  const bool use_part = (ws_size >= need);
  if (!use_part) gpart = nullptr;

  if (use_part) {
    // G fully overwritten by k2; only r needs zeroing (atomic accumulate)
    k0_zero<<<(B_ * 128 + 255) / 256, 256, 0, stream>>>(r, B_ * 128);
  } else {
    const int nzero = B_ * 16384 + B_ * 128;   // G + r contiguous
    k0_zero<<<(nzero + 255) / 256, 256, 0, stream>>>(G, nzero);
  }
  k1_gram<<<B_ * NCH_ + 96, 256, 0, stream>>>(
      x1, we, wk, bk, be, wf, wv, bv, bfv, wo,
      G, r, wkp, wvp, bkp, bvp, wobf, gpart);
  if (use_part)
    k2_reduce<<<(B_ * 16384) / (256 * 4), 256, 0, stream>>>(gpart, G);
  k3_softmax<<<B_ * 64, 128, 0, stream>>>(wq, bq, G, r, wkp, wvp, bkp, bvp, attw, attb);
  k4_out<<<B_ * (T_ / 128), 256, 0, stream>>>(x1, mask, wobf, bo, attw, attb, out);
}

// Round 5
// 394.901 us; speedup vs baseline: 1.1030x; 1.1030x over previous
//
#include <hip/hip_runtime.h>
#include <stdint.h>
#include <stddef.h>

#define B_ 8
#define D_ 128
#define T_ 32768
#define C_ 64
#define NCH_ 128      // t-chunks per batch in k1; Tc = 256

typedef __bf16 bf16;
typedef __bf16 bf16x4 __attribute__((ext_vector_type(4)));
typedef __bf16 bf16x8 __attribute__((ext_vector_type(8)));
typedef float f32x2 __attribute__((ext_vector_type(2)));
typedef float f32x4 __attribute__((ext_vector_type(4)));
typedef float f32x16 __attribute__((ext_vector_type(16)));

__device__ __forceinline__ f32x16 zero16() {
  f32x16 z;
#pragma unroll
  for (int i = 0; i < 16; ++i) z[i] = 0.f;
  return z;
}

// ---------------------------------------------------------------------------
// K0: zero helper (split-K path only needs r zeroed; fallback zeroes G too)
// ---------------------------------------------------------------------------
__global__ __launch_bounds__(256) void k0_zero(float* __restrict__ p, int n)
{
  int i = blockIdx.x * 256 + threadIdx.x;
  if (i < n) p[i] = 0.f;
}

// ---------------------------------------------------------------------------
// K1: Gram partials via LDS-staged tiles. KEY CHANGE vs prior rounds: every
//     global load instruction covers ONE FULL 1KB row-chunk (64 lanes x
//     f32x4) instead of 256B slices across many rows -> escapes the 2^17-
//     stride DRAM alias that capped effective BW at ~2.3 TB/s.
//     gpart slot uses a PRIVATE lane-major layout (1KB contiguous stores);
//     k2 un-permutes. Row-sums r via cheap atomics. 96 extra blocks fold
//     weights as before. Fallback (gpart==nullptr): atomicAdd into G
//     (standard layout).
// ---------------------------------------------------------------------------
__global__ __launch_bounds__(256, 2) void k1_gram(
    const float* __restrict__ x1,
    const float* __restrict__ we, const float* __restrict__ wk,
    const float* __restrict__ bk, const float* __restrict__ be,
    const float* __restrict__ wf, const float* __restrict__ wv,
    const float* __restrict__ bv, const float* __restrict__ bfv,
    const float* __restrict__ wo,
    float* __restrict__ G, float* __restrict__ r,
    float* __restrict__ wkp, float* __restrict__ wvp,
    float* __restrict__ bkp, float* __restrict__ bvp,
    bf16* __restrict__ wobf,
    float* __restrict__ gpart)
{
  const int blk = blockIdx.x;
  const int tid = threadIdx.x;
  const int ngram = B_ * NCH_;   // 1024

  if (blk >= ngram) {
    const int wb = blk - ngram;  // 0..95
    if (wb < 64) {               // folded weights
      const float* wa  = (wb < 32) ? we : wf;
      const float* wb2 = (wb < 32) ? wk : wv;
      float* outw      = (wb < 32) ? wkp : wvp;
      const int idx = (wb & 31) * 256 + tid;   // 0..8191
      const int o = idx >> 7, d = idx & 127;
      float s = 0.f;
      for (int c = 0; c < 64; ++c) s += wa[o * 64 + c] * wb2[c * 128 + d];
      outw[idx] = s;
      if (tid < 64) {
        if (wb == 0) {
          float t = 0.f;
          for (int c = 0; c < 64; ++c) t += we[tid * 64 + c] * bk[c];
          bkp[tid] = t + be[tid];
        } else if (wb == 32) {
          float t = 0.f;
          for (int c = 0; c < 64; ++c) t += wf[tid * 64 + c] * bv[c];
          bvp[tid] = t + bfv[tid];
        }
      }
    } else {                     // wo -> bf16
      const int idx = (wb - 64) * 256 + tid;
      wobf[idx] = (bf16)wo[idx];
    }
    return;
  }

  __shared__ bf16 x_s[128 * 264];  // [d][t], pad 256->264 (16B-aligned rows)

  const int b  = blk >> 7;                   // NCH_ = 128
  const int ch = blk & (NCH_ - 1);
  const int t0 = ch * (T_ / NCH_);           // Tc = 256
  const int wave = tid >> 6, lane = tid & 63;
  const int lrow = lane & 31, lk = lane >> 5;
  const int qa = wave >> 1, qb = wave & 1;   // wave owns 64x64 quadrant

  const float* xb = x1 + (size_t)b * D_ * T_ + t0;

  // ---- staging: wave w loads rows [32w,32w+32); ONE instruction = ONE row
  //      (64 lanes x f32x4 = 1KB contiguous)
#pragma unroll
  for (int g = 0; g < 4; ++g) {
    f32x4 pre[8];
#pragma unroll
    for (int i = 0; i < 8; ++i) {
      const int row = 32 * wave + 8 * g + i;
      pre[i] = *(const f32x4*)(xb + (size_t)row * T_ + 4 * lane);
    }
#pragma unroll
    for (int i = 0; i < 8; ++i) {
      const int row = 32 * wave + 8 * g + i;
      bf16x4 h;
#pragma unroll
      for (int j = 0; j < 4; ++j) h[j] = (bf16)pre[i][j];
      *(bf16x4*)&x_s[row * 264 + 4 * lane] = h;
    }
  }
  __syncthreads();

  // ---- MFMA: 16 k-iters of K=16 over the 256-col tile
  f32x16 acc00 = zero16(), acc01 = zero16(), acc10 = zero16(), acc11 = zero16();
  float rsum = 0.f;

  const bf16* A0  = &x_s[(64 * qa + lrow) * 264 + 8 * lk];
  const bf16* A1  = A0 + 32 * 264;
  const bf16* Bb0 = &x_s[(64 * qb + lrow) * 264 + 8 * lk];
  const bf16* Bb1 = Bb0 + 32 * 264;

#pragma unroll
  for (int k = 0; k < 16; ++k) {
    bf16x8 fa0 = *(const bf16x8*)(A0 + 16 * k);
    bf16x8 fa1 = *(const bf16x8*)(A1 + 16 * k);
    bf16x8 fb0 = *(const bf16x8*)(Bb0 + 16 * k);
    bf16x8 fb1 = *(const bf16x8*)(Bb1 + 16 * k);
    bf16x8 own = qb ? fa1 : fa0;             // row 32*wave+lrow, lk-half cols
#pragma unroll
    for (int j = 0; j < 8; ++j) rsum += (float)own[j];
    acc00 = __builtin_amdgcn_mfma_f32_32x32x16_bf16(fa0, fb0, acc00, 0, 0, 0);
    acc01 = __builtin_amdgcn_mfma_f32_32x32x16_bf16(fa0, fb1, acc01, 0, 0, 0);
    acc10 = __builtin_amdgcn_mfma_f32_32x32x16_bf16(fa1, fb0, acc10, 0, 0, 0);
    acc11 = __builtin_amdgcn_mfma_f32_32x32x16_bf16(fa1, fb1, acc11, 0, 0, 0);
  }

  if (gpart) {
    // private permuted slot: idx = wave*4096 + rr*256 + lane*4 (+q)
    // -> each store instruction = 1KB contiguous. k2 un-permutes.
    float* gp = gpart + (size_t)blk * 16384 + wave * 4096;
#pragma unroll
    for (int rr = 0; rr < 16; ++rr) {
      f32x4 v;
      v[0] = acc00[rr]; v[1] = acc01[rr]; v[2] = acc10[rr]; v[3] = acc11[rr];
      *(f32x4*)(gp + rr * 256 + lane * 4) = v;
    }
  } else {
    float* gb = G + (size_t)b * 16384;
#pragma unroll
    for (int rr = 0; rr < 16; ++rr) {
      const int rloc = (rr & 3) + 8 * (rr >> 2) + 4 * lk;
      const int r0 = 64 * qa + rloc, r1 = 64 * qa + 32 + rloc;
      const int c0 = 64 * qb + lrow, c1 = 64 * qb + 32 + lrow;
      atomicAdd(&gb[r0 * 128 + c0], acc00[rr]);
      atomicAdd(&gb[r0 * 128 + c1], acc01[rr]);
      atomicAdd(&gb[r1 * 128 + c0], acc10[rr]);
      atomicAdd(&gb[r1 * 128 + c1], acc11[rr]);
    }
  }
  float rtot = rsum + __shfl_xor(rsum, 32, 64);
  if (lk == 0) atomicAdd(&r[b * 128 + 32 * wave + lrow], rtot);
}

// ---------------------------------------------------------------------------
// K2: G[b] = sum over NCH_ permuted partials; un-permute on the (tiny,
//     L2-hot) G write. Reads stay fully coalesced f32x4.
// ---------------------------------------------------------------------------
__global__ __launch_bounds__(256) void k2_reduce(
    const float* __restrict__ gpart, float* __restrict__ G)
{
  const int g4 = blockIdx.x * 256 + threadIdx.x;  // 0..32767 (4 floats each)
  const int b = g4 >> 12;                          // 4096 f32x4 per batch
  const int e4 = g4 & 4095;
  const f32x4* p = (const f32x4*)(gpart + ((size_t)b * NCH_) * 16384) + e4;
  f32x4 s = {0.f, 0.f, 0.f, 0.f};
#pragma unroll 8
  for (int ch = 0; ch < NCH_; ++ch) s += p[(size_t)ch * 4096];

  // un-permute: e4 = wave*1024 + rr*64 + lane
  const int w = e4 >> 10, rr = (e4 >> 6) & 15, lane = e4 & 63;
  const int lk = lane >> 5, lrow = lane & 31;
  const int qa = w >> 1, qb = w & 1;
  const int rloc = (rr & 3) + 8 * (rr >> 2) + 4 * lk;
  const int r0 = 64 * qa + rloc, c0 = 64 * qb + lrow;
  float* Gb = G + (size_t)b * 16384;
  Gb[r0 * 128 + c0]               = s[0];
  Gb[r0 * 128 + c0 + 32]          = s[1];
  Gb[(r0 + 32) * 128 + c0]        = s[2];
  Gb[(r0 + 32) * 128 + c0 + 32]   = s[3];
}

// ---------------------------------------------------------------------------
// K3: per (b, c): S[c,:] = wq_c G wk'^T + exact bias terms (via r),
//     P = softmax(S/8), att_w[c,:] = P @ wv' (bf16), att_b[c] = P @ bv'
// ---------------------------------------------------------------------------
__global__ __launch_bounds__(128) void k3_softmax(
    const float* __restrict__ wq, const float* __restrict__ bq,
    const float* __restrict__ G, const float* __restrict__ r,
    const float* __restrict__ wkp, const float* __restrict__ wvp,
    const float* __restrict__ bkp, const float* __restrict__ bvp,
    bf16* __restrict__ attw, float* __restrict__ attb)
{
  const int b = blockIdx.x >> 6, c = blockIdx.x & 63;
  const int tid = threadIdx.x;
  __shared__ float sM[128], sR[128], sQ[128], sP[64];
  __shared__ float sRed;

  const float* Gb = G + (size_t)b * 16384;
  const float* wqc = wq + c * 128;

  const float rv = r[b * 128 + tid];
  sR[tid] = rv;
  float m = 0.f;
  for (int j = 0; j < 128; ++j) m += wqc[j] * Gb[j * 128 + tid];
  sM[tid] = m;
  sQ[tid] = wqc[tid] * rv;
  __syncthreads();

  if (tid < 64) {
    float q2 = sQ[tid] + sQ[tid + 64];
#pragma unroll
    for (int off = 32; off; off >>= 1) q2 += __shfl_xor(q2, off, 64);
    if (tid == 0) sRed = q2;
  }
  __syncthreads();
  const float qr = sRed;
  const float bqc = bq[c];

  if (tid < 64) {
    const int k = tid;
    float s = 0.f, wkr = 0.f;
    for (int i = 0; i < 128; ++i) {
      const float w = wkp[k * 128 + i];
      s += sM[i] * w;
      wkr += sR[i] * w;
    }
    const float bk2 = bkp[k];
    float logit = (s + bqc * wkr + bk2 * qr + (float)T_ * bqc * bk2) * 0.125f;
    float mx = logit;
#pragma unroll
    for (int off = 32; off; off >>= 1) mx = fmaxf(mx, __shfl_xor(mx, off, 64));
    const float e = __expf(logit - mx);
    float sum = e;
#pragma unroll
    for (int off = 32; off; off >>= 1) sum += __shfl_xor(sum, off, 64);
    sP[k] = e / sum;
  }
  __syncthreads();

  {
    float aw = 0.f;
    for (int k = 0; k < 64; ++k) aw += sP[k] * wvp[k * 128 + tid];
    attw[((size_t)b * 64 + c) * 128 + tid] = (bf16)aw;
  }
  if (tid < 64) {
    float pb = sP[tid] * bvp[tid];
#pragma unroll
    for (int off = 32; off; off >>= 1) pb += __shfl_xor(pb, off, 64);
    if (tid == 0) attb[b * 64 + c] = pb;
  }
}

// ---------------------------------------------------------------------------
// K4: fused output, fully long-chunk global access. Per (b, 128-t tile):
//   phase1: stage x[128d][128t] -> LDS TRANSPOSED x_st[t][d] bf16; one
//           instruction = one full 512B row (64 lanes x f32x2).
//   phase2: m1t[t][c] = relu(x^T attw^T + ab) via MFMA(A=x_st, B=attw^T)
//           -- same content as before, operands swapped.
//   phase3: out = wobf @ m1 + bo (unchanged math), but epilogue bounces
//           through LDS (o_s aliases x_st) so every global store is a full
//           512B row (f32x2/lane). mask applied at o_s write.
// ---------------------------------------------------------------------------
__global__ __launch_bounds__(256, 2) void k4_out(
    const float* __restrict__ x1, const float* __restrict__ mask,
    const bf16* __restrict__ wobf, const float* __restrict__ bo,
    const bf16* __restrict__ attw, const float* __restrict__ attb,
    float* __restrict__ out)
{
  __shared__ __attribute__((aligned(16))) char buf[128 * 136 * 2]; // 34816 B
  bf16*  x_st = (bf16*)buf;        // [128 t][136 d]  (phase 1-2)
  float* o_s  = (float*)buf;       // [64 d][132 t]   (phase 3, aliased)
  __shared__ bf16 m1t[128 * 72];   // [t][c], pad 64->72
  __shared__ float bo_s[128];
  __shared__ float ab_s[64];

  const int b = blockIdx.x >> 8;           // 256 tiles per batch
  const int t0 = (blockIdx.x & 255) << 7;
  const int tid = threadIdx.x;
  const int wave = tid >> 6, lane = tid & 63;
  const int lrow = lane & 31, lk = lane >> 5;

  if (tid < 128) bo_s[tid] = bo[tid];
  if (tid < 64) ab_s[tid] = attb[b * 64 + tid];

  // ---- phase 1: stage x -> x_st[t][d] (transposed). One instr = one row.
  const float* xb = x1 + (size_t)b * D_ * T_ + t0;
#pragma unroll
  for (int g = 0; g < 4; ++g) {
    f32x2 pr[8];
#pragma unroll
    for (int i = 0; i < 8; ++i) {
      const int d = 32 * wave + 8 * g + i;
      pr[i] = *(const f32x2*)(xb + (size_t)d * T_ + 2 * lane);
    }
#pragma unroll
    for (int i = 0; i < 8; ++i) {
      const int d = 32 * wave + 8 * g + i;
      x_st[(2 * lane) * 136 + d]     = (bf16)pr[i][0];
      x_st[(2 * lane + 1) * 136 + d] = (bf16)pr[i][1];
    }
  }
  __syncthreads();

  // ---- phase 2: m1t[t][c] = relu(sum_d x[d][t] attw[c][d] + ab[c])
  const bf16* awb = attw + (size_t)b * 8192;
  f32x16 m0 = zero16(), m1a = zero16();
  const bf16* ax = &x_st[(32 * wave + lrow) * 136 + 8 * lk];
#pragma unroll
  for (int ki = 0; ki < 8; ++ki) {
    bf16x8 af = *(const bf16x8*)(ax + 16 * ki);
    bf16x8 b0 = *(const bf16x8*)(awb + (size_t)lrow * 128 + 16 * ki + 8 * lk);
    bf16x8 b1 = *(const bf16x8*)(awb + (size_t)(32 + lrow) * 128 + 16 * ki + 8 * lk);
    m0  = __builtin_amdgcn_mfma_f32_32x32x16_bf16(af, b0, m0, 0, 0, 0);
    m1a = __builtin_amdgcn_mfma_f32_32x32x16_bf16(af, b1, m1a, 0, 0, 0);
  }
#pragma unroll
  for (int rr = 0; rr < 16; ++rr) {
    const int tl = 32 * wave + (rr & 3) + 8 * (rr >> 2) + 4 * lk;
    m1t[tl * 72 + lrow]      = (bf16)fmaxf(m0[rr]  + ab_s[lrow], 0.f);
    m1t[tl * 72 + 32 + lrow] = (bf16)fmaxf(m1a[rr] + ab_s[32 + lrow], 0.f);
  }
  __syncthreads();   // all x_st reads + m1t writes done

  // ---- phase 3: out[d][t] = wobf[d][c] m1[c][t] + bo, masked
  f32x16 q0 = zero16(), q1 = zero16(), q2 = zero16(), q3 = zero16();
  const bf16* mrow = &m1t[(32 * wave + lrow) * 72];
#pragma unroll
  for (int k0 = 0; k0 < 4; ++k0) {
    bf16x8 bm = *(const bf16x8*)(mrow + 16 * k0 + 8 * lk);
    bf16x8 w0 = *(const bf16x8*)(wobf + (size_t)(lrow) * 64 + 16 * k0 + 8 * lk);
    bf16x8 w1 = *(const bf16x8*)(wobf + (size_t)(32 + lrow) * 64 + 16 * k0 + 8 * lk);
    bf16x8 w2 = *(const bf16x8*)(wobf + (size_t)(64 + lrow) * 64 + 16 * k0 + 8 * lk);
    bf16x8 w3 = *(const bf16x8*)(wobf + (size_t)(96 + lrow) * 64 + 16 * k0 + 8 * lk);
    q0 = __builtin_amdgcn_mfma_f32_32x32x16_bf16(w0, bm, q0, 0, 0, 0);
    q1 = __builtin_amdgcn_mfma_f32_32x32x16_bf16(w1, bm, q1, 0, 0, 0);
    q2 = __builtin_amdgcn_mfma_f32_32x32x16_bf16(w2, bm, q2, 0, 0, 0);
    q3 = __builtin_amdgcn_mfma_f32_32x32x16_bf16(w3, bm, q3, 0, 0, 0);
  }

  const int tl = 32 * wave + lrow;
  const float mv = mask[(size_t)b * T_ + t0 + tl];
  float* ob = out + (size_t)b * D_ * T_ + t0;

  // half 0: d in [0,64)  (q0: d=rloc, q1: d=32+rloc)
#pragma unroll
  for (int rr = 0; rr < 16; ++rr) {
    const int rloc = (rr & 3) + 8 * (rr >> 2) + 4 * lk;
    o_s[rloc * 132 + tl]        = (q0[rr] + bo_s[rloc]) * mv;
    o_s[(32 + rloc) * 132 + tl] = (q1[rr] + bo_s[32 + rloc]) * mv;
  }
  __syncthreads();
#pragma unroll
  for (int i = 0; i < 16; ++i) {
    const int dl = 16 * wave + i;
    f32x2 v = *(const f32x2*)(o_s + dl * 132 + 2 * lane);
    *(f32x2*)(ob + (size_t)dl * T_ + 2 * lane) = v;
  }
  __syncthreads();

  // half 1: d in [64,128)  (q2: d=64+rloc, q3: d=96+rloc)
#pragma unroll
  for (int rr = 0; rr < 16; ++rr) {
    const int rloc = (rr & 3) + 8 * (rr >> 2) + 4 * lk;
    o_s[rloc * 132 + tl]        = (q2[rr] + bo_s[64 + rloc]) * mv;
    o_s[(32 + rloc) * 132 + tl] = (q3[rr] + bo_s[96 + rloc]) * mv;
  }
  __syncthreads();
#pragma unroll
  for (int i = 0; i < 16; ++i) {
    const int dl = 16 * wave + i;
    f32x2 v = *(const f32x2*)(o_s + dl * 132 + 2 * lane);
    *(f32x2*)(ob + (size_t)(64 + dl) * T_ + 2 * lane) = v;
  }
}

// ---------------------------------------------------------------------------
// Workspace: small buffers ~0.75 MB, gpart 1024*64KB = 67 MB (split-K).
// Fallback to atomic path if ws too small.
// ---------------------------------------------------------------------------
extern "C" void kernel_launch(void* const* d_in, const int* in_sizes, int n_in,
                              void* d_out, int out_size, void* d_ws, size_t ws_size,
                              hipStream_t stream)
{
  const float* x1   = (const float*)d_in[0];
  // d_in[1] = x2 (unused in encoder stage)
  const float* mask = (const float*)d_in[2];
  const float* wq   = (const float*)d_in[3];
  const float* bq   = (const float*)d_in[4];
  const float* wk   = (const float*)d_in[5];
  const float* bk   = (const float*)d_in[6];
  const float* wv   = (const float*)d_in[7];
  const float* bv   = (const float*)d_in[8];
  const float* we   = (const float*)d_in[9];
  const float* be   = (const float*)d_in[10];
  const float* wf   = (const float*)d_in[11];
  const float* bfv  = (const float*)d_in[12];
  const float* wo   = (const float*)d_in[13];
  const float* bo   = (const float*)d_in[14];
  float* out = (float*)d_out;

  char* base = (char*)d_ws;
  size_t off = 0;
  float* G    = (float*)(base + off); off += (size_t)B_ * 16384 * 4;
  float* r    = (float*)(base + off); off += (size_t)B_ * 128 * 4;
  float* wkp  = (float*)(base + off); off += 8192 * 4;
  float* wvp  = (float*)(base + off); off += 8192 * 4;
  float* bkp  = (float*)(base + off); off += 64 * 4;
  float* bvp  = (float*)(base + off); off += 64 * 4;
  float* attb = (float*)(base + off); off += (size_t)B_ * 64 * 4;
  bf16* attw  = (bf16*)(base + off);  off += (size_t)B_ * 64 * 128 * 2;
  bf16* wobf  = (bf16*)(base + off);  off += 8192 * 2;
  off = (off + 15) & ~(size_t)15;
  float* gpart = (float*)(base + off);
  const size_t need = off + (size_t)B_ * NCH_ * 16384 * 4;
  const bool use_part = (ws_size >= need);
  if (!use_part) gpart = nullptr;

  if (use_part) {
    k0_zero<<<(B_ * 128 + 255) / 256, 256, 0, stream>>>(r, B_ * 128);
  } else {
    const int nzero = B_ * 16384 + B_ * 128;   // G + r contiguous
    k0_zero<<<(nzero + 255) / 256, 256, 0, stream>>>(G, nzero);
  }
  k1_gram<<<B_ * NCH_ + 96, 256, 0, stream>>>(
      x1, we, wk, bk, be, wf, wv, bv, bfv, wo,
      G, r, wkp, wvp, bkp, bvp, wobf, gpart);
  if (use_part)
    k2_reduce<<<(B_ * 16384) / (256 * 4), 256, 0, stream>>>(gpart, G);
  k3_softmax<<<B_ * 64, 128, 0, stream>>>(wq, bq, G, r, wkp, wvp, bkp, bvp, attw, attb);
  k4_out<<<B_ * (T_ / 128), 256, 0, stream>>>(x1, mask, wobf, bo, attw, attb, out);
}

// Round 6
// 375.707 us; speedup vs baseline: 1.1594x; 1.0511x over previous
//
#include <hip/hip_runtime.h>
#include <stdint.h>
#include <stddef.h>

#define B_ 8
#define D_ 128
#define T_ 32768
#define C_ 64
#define NCH_ 64       // t-chunks per batch in k1; Tc = 512 (2 substages of 256)

typedef __bf16 bf16;
typedef __bf16 bf16x4 __attribute__((ext_vector_type(4)));
typedef __bf16 bf16x8 __attribute__((ext_vector_type(8)));
typedef float f32x2 __attribute__((ext_vector_type(2)));
typedef float f32x4 __attribute__((ext_vector_type(4)));
typedef float f32x16 __attribute__((ext_vector_type(16)));

__device__ __forceinline__ f32x16 zero16() {
  f32x16 z;
#pragma unroll
  for (int i = 0; i < 16; ++i) z[i] = 0.f;
  return z;
}

// ---------------------------------------------------------------------------
// K0: zero helper (split-K path only needs r zeroed; fallback zeroes G too)
// ---------------------------------------------------------------------------
__global__ __launch_bounds__(256) void k0_zero(float* __restrict__ p, int n)
{
  int i = blockIdx.x * 256 + threadIdx.x;
  if (i < n) p[i] = 0.f;
}

// ---------------------------------------------------------------------------
// K1: Gram partials via LDS-staged tiles; every global load instruction is
//     ONE FULL 1KB row-chunk (64 lanes x f32x4) -> avoids the 2^17-stride
//     alias that capped BW at ~2.3 TB/s in R0-R4. Tc=512 in two 256-col
//     substages accumulating into the same accs (halves gpart vs NCH=128).
//     gpart slot uses a PRIVATE lane-major layout (1KB contiguous stores);
//     k2 un-permutes. Row-sums r via cheap atomics. 96 extra blocks fold
//     weights. Fallback (gpart==nullptr): atomicAdd into G (std layout).
// ---------------------------------------------------------------------------
__global__ __launch_bounds__(256, 2) void k1_gram(
    const float* __restrict__ x1,
    const float* __restrict__ we, const float* __restrict__ wk,
    const float* __restrict__ bk, const float* __restrict__ be,
    const float* __restrict__ wf, const float* __restrict__ wv,
    const float* __restrict__ bv, const float* __restrict__ bfv,
    const float* __restrict__ wo,
    float* __restrict__ G, float* __restrict__ r,
    float* __restrict__ wkp, float* __restrict__ wvp,
    float* __restrict__ bkp, float* __restrict__ bvp,
    bf16* __restrict__ wobf,
    float* __restrict__ gpart)
{
  const int blk = blockIdx.x;
  const int tid = threadIdx.x;
  const int ngram = B_ * NCH_;   // 512

  if (blk >= ngram) {
    const int wb = blk - ngram;  // 0..95
    if (wb < 64) {               // folded weights
      const float* wa  = (wb < 32) ? we : wf;
      const float* wb2 = (wb < 32) ? wk : wv;
      float* outw      = (wb < 32) ? wkp : wvp;
      const int idx = (wb & 31) * 256 + tid;   // 0..8191
      const int o = idx >> 7, d = idx & 127;
      float s = 0.f;
      for (int c = 0; c < 64; ++c) s += wa[o * 64 + c] * wb2[c * 128 + d];
      outw[idx] = s;
      if (tid < 64) {
        if (wb == 0) {
          float t = 0.f;
          for (int c = 0; c < 64; ++c) t += we[tid * 64 + c] * bk[c];
          bkp[tid] = t + be[tid];
        } else if (wb == 32) {
          float t = 0.f;
          for (int c = 0; c < 64; ++c) t += wf[tid * 64 + c] * bv[c];
          bvp[tid] = t + bfv[tid];
        }
      }
    } else {                     // wo -> bf16
      const int idx = (wb - 64) * 256 + tid;
      wobf[idx] = (bf16)wo[idx];
    }
    return;
  }

  __shared__ bf16 x_s[128 * 264];  // [d][t], pad 256->264 (16B-aligned rows)

  const int b  = blk / NCH_;
  const int ch = blk & (NCH_ - 1);
  const int t0 = ch * (T_ / NCH_);           // Tc = 512
  const int wave = tid >> 6, lane = tid & 63;
  const int lrow = lane & 31, lk = lane >> 5;
  const int qa = wave >> 1, qb = wave & 1;   // wave owns 64x64 quadrant

  const float* xb = x1 + (size_t)b * D_ * T_ + t0;

  f32x16 acc00 = zero16(), acc01 = zero16(), acc10 = zero16(), acc11 = zero16();
  float rsum = 0.f;

  const bf16* A0  = &x_s[(64 * qa + lrow) * 264 + 8 * lk];
  const bf16* A1  = A0 + 32 * 264;
  const bf16* Bb0 = &x_s[(64 * qb + lrow) * 264 + 8 * lk];
  const bf16* Bb1 = Bb0 + 32 * 264;

  for (int s = 0; s < 2; ++s) {              // two 256-col substages
    const float* xs = xb + s * 256;
    if (s) __syncthreads();                  // prev-substage MFMA reads done
    // staging: wave w loads its rows [32w,32w+32); ONE instr = ONE row
    // (64 lanes x f32x4 = 1KB contiguous)
#pragma unroll
    for (int g = 0; g < 4; ++g) {
      f32x4 pre[8];
#pragma unroll
      for (int i = 0; i < 8; ++i) {
        const int row = 32 * wave + 8 * g + i;
        pre[i] = *(const f32x4*)(xs + (size_t)row * T_ + 4 * lane);
      }
#pragma unroll
      for (int i = 0; i < 8; ++i) {
        const int row = 32 * wave + 8 * g + i;
        bf16x4 h;
#pragma unroll
        for (int j = 0; j < 4; ++j) h[j] = (bf16)pre[i][j];
        *(bf16x4*)&x_s[row * 264 + 4 * lane] = h;
      }
    }
    __syncthreads();
    // MFMA: 16 k-iters of K=16 over this 256-col substage
#pragma unroll
    for (int k = 0; k < 16; ++k) {
      bf16x8 fa0 = *(const bf16x8*)(A0 + 16 * k);
      bf16x8 fa1 = *(const bf16x8*)(A1 + 16 * k);
      bf16x8 fb0 = *(const bf16x8*)(Bb0 + 16 * k);
      bf16x8 fb1 = *(const bf16x8*)(Bb1 + 16 * k);
      bf16x8 own = qb ? fa1 : fa0;           // row 32*wave+lrow, lk-half cols
#pragma unroll
      for (int j = 0; j < 8; ++j) rsum += (float)own[j];
      acc00 = __builtin_amdgcn_mfma_f32_32x32x16_bf16(fa0, fb0, acc00, 0, 0, 0);
      acc01 = __builtin_amdgcn_mfma_f32_32x32x16_bf16(fa0, fb1, acc01, 0, 0, 0);
      acc10 = __builtin_amdgcn_mfma_f32_32x32x16_bf16(fa1, fb0, acc10, 0, 0, 0);
      acc11 = __builtin_amdgcn_mfma_f32_32x32x16_bf16(fa1, fb1, acc11, 0, 0, 0);
    }
  }

  if (gpart) {
    // private permuted slot: idx = wave*4096 + rr*256 + lane*4
    // -> each store instruction = 1KB contiguous. k2 un-permutes.
    float* gp = gpart + (size_t)blk * 16384 + wave * 4096;
#pragma unroll
    for (int rr = 0; rr < 16; ++rr) {
      f32x4 v;
      v[0] = acc00[rr]; v[1] = acc01[rr]; v[2] = acc10[rr]; v[3] = acc11[rr];
      *(f32x4*)(gp + rr * 256 + lane * 4) = v;
    }
  } else {
    float* gb = G + (size_t)b * 16384;
#pragma unroll
    for (int rr = 0; rr < 16; ++rr) {
      const int rloc = (rr & 3) + 8 * (rr >> 2) + 4 * lk;
      const int r0 = 64 * qa + rloc, r1 = 64 * qa + 32 + rloc;
      const int c0 = 64 * qb + lrow, c1 = 64 * qb + 32 + lrow;
      atomicAdd(&gb[r0 * 128 + c0], acc00[rr]);
      atomicAdd(&gb[r0 * 128 + c1], acc01[rr]);
      atomicAdd(&gb[r1 * 128 + c0], acc10[rr]);
      atomicAdd(&gb[r1 * 128 + c1], acc11[rr]);
    }
  }
  float rtot = rsum + __shfl_xor(rsum, 32, 64);
  if (lk == 0) atomicAdd(&r[b * 128 + 32 * wave + lrow], rtot);
}

// ---------------------------------------------------------------------------
// K2: G[b] = sum over NCH_ permuted partials; un-permute on the (tiny,
//     L2-hot) G write. Reads stay fully coalesced f32x4.
// ---------------------------------------------------------------------------
__global__ __launch_bounds__(256) void k2_reduce(
    const float* __restrict__ gpart, float* __restrict__ G)
{
  const int g4 = blockIdx.x * 256 + threadIdx.x;  // 0..32767 (4 floats each)
  const int b = g4 >> 12;                          // 4096 f32x4 per batch
  const int e4 = g4 & 4095;
  const f32x4* p = (const f32x4*)(gpart + ((size_t)b * NCH_) * 16384) + e4;
  f32x4 s = {0.f, 0.f, 0.f, 0.f};
#pragma unroll 8
  for (int ch = 0; ch < NCH_; ++ch) s += p[(size_t)ch * 4096];

  // un-permute: e4 = wave*1024 + rr*64 + lane
  const int w = e4 >> 10, rr = (e4 >> 6) & 15, lane = e4 & 63;
  const int lk = lane >> 5, lrow = lane & 31;
  const int qa = w >> 1, qb = w & 1;
  const int rloc = (rr & 3) + 8 * (rr >> 2) + 4 * lk;
  const int r0 = 64 * qa + rloc, c0 = 64 * qb + lrow;
  float* Gb = G + (size_t)b * 16384;
  Gb[r0 * 128 + c0]               = s[0];
  Gb[r0 * 128 + c0 + 32]          = s[1];
  Gb[(r0 + 32) * 128 + c0]        = s[2];
  Gb[(r0 + 32) * 128 + c0 + 32]   = s[3];
}

// ---------------------------------------------------------------------------
// K3: per (b, c): S[c,:] = wq_c G wk'^T + exact bias terms (via r),
//     P = softmax(S/8), att_w[c,:] = P @ wv' (bf16), att_b[c] = P @ bv'
// ---------------------------------------------------------------------------
__global__ __launch_bounds__(128) void k3_softmax(
    const float* __restrict__ wq, const float* __restrict__ bq,
    const float* __restrict__ G, const float* __restrict__ r,
    const float* __restrict__ wkp, const float* __restrict__ wvp,
    const float* __restrict__ bkp, const float* __restrict__ bvp,
    bf16* __restrict__ attw, float* __restrict__ attb)
{
  const int b = blockIdx.x >> 6, c = blockIdx.x & 63;
  const int tid = threadIdx.x;
  __shared__ float sM[128], sR[128], sQ[128], sP[64];
  __shared__ float sRed;

  const float* Gb = G + (size_t)b * 16384;
  const float* wqc = wq + c * 128;

  const float rv = r[b * 128 + tid];
  sR[tid] = rv;
  float m = 0.f;
  for (int j = 0; j < 128; ++j) m += wqc[j] * Gb[j * 128 + tid];
  sM[tid] = m;
  sQ[tid] = wqc[tid] * rv;
  __syncthreads();

  if (tid < 64) {
    float q2 = sQ[tid] + sQ[tid + 64];
#pragma unroll
    for (int off = 32; off; off >>= 1) q2 += __shfl_xor(q2, off, 64);
    if (tid == 0) sRed = q2;
  }
  __syncthreads();
  const float qr = sRed;
  const float bqc = bq[c];

  if (tid < 64) {
    const int k = tid;
    float s = 0.f, wkr = 0.f;
    for (int i = 0; i < 128; ++i) {
      const float w = wkp[k * 128 + i];
      s += sM[i] * w;
      wkr += sR[i] * w;
    }
    const float bk2 = bkp[k];
    float logit = (s + bqc * wkr + bk2 * qr + (float)T_ * bqc * bk2) * 0.125f;
    float mx = logit;
#pragma unroll
    for (int off = 32; off; off >>= 1) mx = fmaxf(mx, __shfl_xor(mx, off, 64));
    const float e = __expf(logit - mx);
    float sum = e;
#pragma unroll
    for (int off = 32; off; off >>= 1) sum += __shfl_xor(sum, off, 64);
    sP[k] = e / sum;
  }
  __syncthreads();

  {
    float aw = 0.f;
    for (int k = 0; k < 64; ++k) aw += sP[k] * wvp[k * 128 + tid];
    attw[((size_t)b * 64 + c) * 128 + tid] = (bf16)aw;
  }
  if (tid < 64) {
    float pb = sP[tid] * bvp[tid];
#pragma unroll
    for (int off = 32; off; off >>= 1) pb += __shfl_xor(pb, off, 64);
    if (tid == 0) attb[b * 64 + c] = pb;
  }
}

// ---------------------------------------------------------------------------
// K4 v3: R2's proven compute path (direct global x dword loads, per-lane m1
//   rows, no compute barriers) + LDS-bounced OUTPUT so every global store is
//   one 512B contiguous row-chunk (64 lanes x f32x2). o_s[64][132] is
//   ALIASED over m1 (dead after stage 2) -> LDS 34.6KB, 4 blocks/CU.
// ---------------------------------------------------------------------------
__global__ __launch_bounds__(256, 4) void k4_out(
    const float* __restrict__ x1, const float* __restrict__ mask,
    const bf16* __restrict__ wobf, const float* __restrict__ bo,
    const bf16* __restrict__ attw, const float* __restrict__ attb,
    float* __restrict__ out)
{
  __shared__ __attribute__((aligned(16))) char ubuf[64 * 132 * 4]; // 33792 B
  bf16*  m1  = (bf16*)ubuf;        // [128 t][72 c]   (stages 1-2)
  float* o_s = (float*)ubuf;       // [64 d][132 t]   (epilogue, aliased)
  __shared__ float bo_s[128];
  __shared__ float ab_s[64];

  const int b = blockIdx.x >> 8;           // 256 tiles per batch
  const int t0 = (blockIdx.x & 255) << 7;
  const int tid = threadIdx.x;
  const int wave = tid >> 6, lane = tid & 63;
  const int lrow = lane & 31, lk = lane >> 5;
  const int tcol = 32 * wave + lrow;

  if (tid < 128) bo_s[tid] = bo[tid];
  if (tid < 64) ab_s[tid] = attb[b * 64 + tid];
  __syncthreads();

  const float* xc = x1 + (size_t)b * D_ * T_ + t0 + tcol;   // column base
  const bf16* awb = attw + (size_t)b * 8192;

  // ---- stage 1: M1[c][t] = attw[c][d] * x[d][t]
  f32x16 p0 = zero16(), p1 = zero16();
#pragma unroll
  for (int k0 = 0; k0 < 8; ++k0) {
    bf16x8 a0 = *(const bf16x8*)(awb + (size_t)lrow * 128 + 16 * k0 + 8 * lk);
    bf16x8 a1 = *(const bf16x8*)(awb + (size_t)(32 + lrow) * 128 + 16 * k0 + 8 * lk);
    bf16x8 bx;
#pragma unroll
    for (int j = 0; j < 8; ++j)
      bx[j] = (bf16)xc[(size_t)(16 * k0 + 8 * lk + j) * T_];
    p0 = __builtin_amdgcn_mfma_f32_32x32x16_bf16(a0, bx, p0, 0, 0, 0);
    p1 = __builtin_amdgcn_mfma_f32_32x32x16_bf16(a1, bx, p1, 0, 0, 0);
  }
  bf16* mrow = &m1[tcol * 72];              // this lane's own t-row
#pragma unroll
  for (int rr = 0; rr < 16; ++rr) {
    const int row = (rr & 3) + 8 * (rr >> 2) + 4 * lk;
    mrow[row]      = (bf16)fmaxf(p0[rr] + ab_s[row], 0.f);
    mrow[32 + row] = (bf16)fmaxf(p1[rr] + ab_s[32 + row], 0.f);
  }

  // ---- stage 2: out[d][t] = wobf[d][c] * m1[c][t] (own row, no barrier)
  f32x16 q0 = zero16(), q1 = zero16(), q2 = zero16(), q3 = zero16();
#pragma unroll
  for (int k0 = 0; k0 < 4; ++k0) {
    bf16x8 bm = *(const bf16x8*)(mrow + 16 * k0 + 8 * lk);
    bf16x8 w0 = *(const bf16x8*)(wobf + (size_t)(lrow) * 64 + 16 * k0 + 8 * lk);
    bf16x8 w1 = *(const bf16x8*)(wobf + (size_t)(32 + lrow) * 64 + 16 * k0 + 8 * lk);
    bf16x8 w2 = *(const bf16x8*)(wobf + (size_t)(64 + lrow) * 64 + 16 * k0 + 8 * lk);
    bf16x8 w3 = *(const bf16x8*)(wobf + (size_t)(96 + lrow) * 64 + 16 * k0 + 8 * lk);
    q0 = __builtin_amdgcn_mfma_f32_32x32x16_bf16(w0, bm, q0, 0, 0, 0);
    q1 = __builtin_amdgcn_mfma_f32_32x32x16_bf16(w1, bm, q1, 0, 0, 0);
    q2 = __builtin_amdgcn_mfma_f32_32x32x16_bf16(w2, bm, q2, 0, 0, 0);
    q3 = __builtin_amdgcn_mfma_f32_32x32x16_bf16(w3, bm, q3, 0, 0, 0);
  }

  // ---- epilogue: bounce through o_s so stores are full 512B row-chunks
  const float mv = mask[(size_t)b * T_ + t0 + tcol];
  float* ob = out + (size_t)b * D_ * T_ + t0;

  __syncthreads();                 // all m1 reads done before o_s overwrite
  // half 0: d in [0,64)
#pragma unroll
  for (int rr = 0; rr < 16; ++rr) {
    const int rloc = (rr & 3) + 8 * (rr >> 2) + 4 * lk;
    o_s[rloc * 132 + tcol]        = (q0[rr] + bo_s[rloc]) * mv;
    o_s[(32 + rloc) * 132 + tcol] = (q1[rr] + bo_s[32 + rloc]) * mv;
  }
  __syncthreads();
#pragma unroll
  for (int i = 0; i < 16; ++i) {
    const int dl = 16 * wave + i;
    f32x2 v = *(const f32x2*)(o_s + dl * 132 + 2 * lane);
    *(f32x2*)(ob + (size_t)dl * T_ + 2 * lane) = v;
  }
  __syncthreads();
  // half 1: d in [64,128)
#pragma unroll
  for (int rr = 0; rr < 16; ++rr) {
    const int rloc = (rr & 3) + 8 * (rr >> 2) + 4 * lk;
    o_s[rloc * 132 + tcol]        = (q2[rr] + bo_s[64 + rloc]) * mv;
    o_s[(32 + rloc) * 132 + tcol] = (q3[rr] + bo_s[96 + rloc]) * mv;
  }
  __syncthreads();
#pragma unroll
  for (int i = 0; i < 16; ++i) {
    const int dl = 16 * wave + i;
    f32x2 v = *(const f32x2*)(o_s + dl * 132 + 2 * lane);
    *(f32x2*)(ob + (size_t)(64 + dl) * T_ + 2 * lane) = v;
  }
}

// ---------------------------------------------------------------------------
// Workspace: small buffers ~0.75 MB, gpart 512*64KB = 33.5 MB (split-K).
// Fallback to atomic path if ws too small.
// ---------------------------------------------------------------------------
extern "C" void kernel_launch(void* const* d_in, const int* in_sizes, int n_in,
                              void* d_out, int out_size, void* d_ws, size_t ws_size,
                              hipStream_t stream)
{
  const float* x1   = (const float*)d_in[0];
  // d_in[1] = x2 (unused in encoder stage)
  const float* mask = (const float*)d_in[2];
  const float* wq   = (const float*)d_in[3];
  const float* bq   = (const float*)d_in[4];
  const float* wk   = (const float*)d_in[5];
  const float* bk   = (const float*)d_in[6];
  const float* wv   = (const float*)d_in[7];
  const float* bv   = (const float*)d_in[8];
  const float* we   = (const float*)d_in[9];
  const float* be   = (const float*)d_in[10];
  const float* wf   = (const float*)d_in[11];
  const float* bfv  = (const float*)d_in[12];
  const float* wo   = (const float*)d_in[13];
  const float* bo   = (const float*)d_in[14];
  float* out = (float*)d_out;

  char* base = (char*)d_ws;
  size_t off = 0;
  float* G    = (float*)(base + off); off += (size_t)B_ * 16384 * 4;
  float* r    = (float*)(base + off); off += (size_t)B_ * 128 * 4;
  float* wkp  = (float*)(base + off); off += 8192 * 4;
  float* wvp  = (float*)(base + off); off += 8192 * 4;
  float* bkp  = (float*)(base + off); off += 64 * 4;
  float* bvp  = (float*)(base + off); off += 64 * 4;
  float* attb = (float*)(base + off); off += (size_t)B_ * 64 * 4;
  bf16* attw  = (bf16*)(base + off);  off += (size_t)B_ * 64 * 128 * 2;
  bf16* wobf  = (bf16*)(base + off);  off += 8192 * 2;
  off = (off + 15) & ~(size_t)15;
  float* gpart = (float*)(base + off);
  const size_t need = off + (size_t)B_ * NCH_ * 16384 * 4;
  const bool use_part = (ws_size >= need);
  if (!use_part) gpart = nullptr;

  if (use_part) {
    k0_zero<<<(B_ * 128 + 255) / 256, 256, 0, stream>>>(r, B_ * 128);
  } else {
    const int nzero = B_ * 16384 + B_ * 128;   // G + r contiguous
    k0_zero<<<(nzero + 255) / 256, 256, 0, stream>>>(G, nzero);
  }
  k1_gram<<<B_ * NCH_ + 96, 256, 0, stream>>>(
      x1, we, wk, bk, be, wf, wv, bv, bfv, wo,
      G, r, wkp, wvp, bkp, bvp, wobf, gpart);
  if (use_part)
    k2_reduce<<<(B_ * 16384) / (256 * 4), 256, 0, stream>>>(gpart, G);
  k3_softmax<<<B_ * 64, 128, 0, stream>>>(wq, bq, G, r, wkp, wvp, bkp, bvp, attw, attb);
  k4_out<<<B_ * (T_ / 128), 256, 0, stream>>>(x1, mask, wobf, bo, attw, attb, out);
}

// Round 7
// 370.947 us; speedup vs baseline: 1.1743x; 1.0128x over previous
//
#include <hip/hip_runtime.h>
#include <stdint.h>
#include <stddef.h>

#define B_ 8
#define D_ 128
#define T_ 32768
#define C_ 64
#define NCH_ 64       // t-chunks per batch in k1; Tc = 512 (2 substages of 256)

typedef __bf16 bf16;
typedef __bf16 bf16x2 __attribute__((ext_vector_type(2)));
typedef __bf16 bf16x4 __attribute__((ext_vector_type(4)));
typedef __bf16 bf16x8 __attribute__((ext_vector_type(8)));
typedef float f32x2 __attribute__((ext_vector_type(2)));
typedef float f32x4 __attribute__((ext_vector_type(4)));
typedef float f32x16 __attribute__((ext_vector_type(16)));

__device__ __forceinline__ f32x16 zero16() {
  f32x16 z;
#pragma unroll
  for (int i = 0; i < 16; ++i) z[i] = 0.f;
  return z;
}

// ---------------------------------------------------------------------------
// K0: zero helper (used only by the atomic fallback path)
// ---------------------------------------------------------------------------
__global__ __launch_bounds__(256) void k0_zero(float* __restrict__ p, int n)
{
  int i = blockIdx.x * 256 + threadIdx.x;
  if (i < n) p[i] = 0.f;
}

// ---------------------------------------------------------------------------
// K1: Gram partials via LDS-staged tiles; every global load instruction is
//     ONE FULL 1KB row-chunk (64 lanes x f32x4) -> avoids the 2^17-stride
//     alias that capped BW at ~2.3 TB/s (R0-R4 evidence). Tc=512 in two
//     256-col substages accumulating into the same accs.
//     gpart slot uses a PRIVATE lane-major layout (1KB contiguous stores);
//     k2 un-permutes. Row-sum partials go to rpart (plain stores; k2
//     reduces -> no atomics, no k0 in main path). 96 extra blocks fold
//     weights. Fallback (gpart==nullptr): atomicAdd into G + r (needs k0).
// ---------------------------------------------------------------------------
__global__ __launch_bounds__(256, 2) void k1_gram(
    const float* __restrict__ x1,
    const float* __restrict__ we, const float* __restrict__ wk,
    const float* __restrict__ bk, const float* __restrict__ be,
    const float* __restrict__ wf, const float* __restrict__ wv,
    const float* __restrict__ bv, const float* __restrict__ bfv,
    const float* __restrict__ wo,
    float* __restrict__ G, float* __restrict__ r,
    float* __restrict__ wkp, float* __restrict__ wvp,
    float* __restrict__ bkp, float* __restrict__ bvp,
    bf16* __restrict__ wobf,
    float* __restrict__ gpart, float* __restrict__ rpart)
{
  const int blk = blockIdx.x;
  const int tid = threadIdx.x;
  const int ngram = B_ * NCH_;   // 512

  if (blk >= ngram) {
    const int wb = blk - ngram;  // 0..95
    if (wb < 64) {               // folded weights
      const float* wa  = (wb < 32) ? we : wf;
      const float* wb2 = (wb < 32) ? wk : wv;
      float* outw      = (wb < 32) ? wkp : wvp;
      const int idx = (wb & 31) * 256 + tid;   // 0..8191
      const int o = idx >> 7, d = idx & 127;
      float s = 0.f;
      for (int c = 0; c < 64; ++c) s += wa[o * 64 + c] * wb2[c * 128 + d];
      outw[idx] = s;
      if (tid < 64) {
        if (wb == 0) {
          float t = 0.f;
          for (int c = 0; c < 64; ++c) t += we[tid * 64 + c] * bk[c];
          bkp[tid] = t + be[tid];
        } else if (wb == 32) {
          float t = 0.f;
          for (int c = 0; c < 64; ++c) t += wf[tid * 64 + c] * bv[c];
          bvp[tid] = t + bfv[tid];
        }
      }
    } else {                     // wo -> bf16
      const int idx = (wb - 64) * 256 + tid;
      wobf[idx] = (bf16)wo[idx];
    }
    return;
  }

  __shared__ bf16 x_s[128 * 264];  // [d][t], pad 256->264 (16B-aligned rows)

  const int b  = blk / NCH_;
  const int ch = blk & (NCH_ - 1);
  const int t0 = ch * (T_ / NCH_);           // Tc = 512
  const int wave = tid >> 6, lane = tid & 63;
  const int lrow = lane & 31, lk = lane >> 5;
  const int qa = wave >> 1, qb = wave & 1;   // wave owns 64x64 quadrant

  const float* xb = x1 + (size_t)b * D_ * T_ + t0;

  f32x16 acc00 = zero16(), acc01 = zero16(), acc10 = zero16(), acc11 = zero16();
  float rsum = 0.f;

  const bf16* A0  = &x_s[(64 * qa + lrow) * 264 + 8 * lk];
  const bf16* A1  = A0 + 32 * 264;
  const bf16* Bb0 = &x_s[(64 * qb + lrow) * 264 + 8 * lk];
  const bf16* Bb1 = Bb0 + 32 * 264;

  for (int s = 0; s < 2; ++s) {              // two 256-col substages
    const float* xs = xb + s * 256;
    if (s) __syncthreads();                  // prev-substage MFMA reads done
    // staging: wave w loads its rows [32w,32w+32); ONE instr = ONE row
    // (64 lanes x f32x4 = 1KB contiguous)
#pragma unroll
    for (int g = 0; g < 4; ++g) {
      f32x4 pre[8];
#pragma unroll
      for (int i = 0; i < 8; ++i) {
        const int row = 32 * wave + 8 * g + i;
        pre[i] = *(const f32x4*)(xs + (size_t)row * T_ + 4 * lane);
      }
#pragma unroll
      for (int i = 0; i < 8; ++i) {
        const int row = 32 * wave + 8 * g + i;
        bf16x4 h;
#pragma unroll
        for (int j = 0; j < 4; ++j) h[j] = (bf16)pre[i][j];
        *(bf16x4*)&x_s[row * 264 + 4 * lane] = h;
      }
    }
    __syncthreads();
    // MFMA: 16 k-iters of K=16 over this 256-col substage
#pragma unroll
    for (int k = 0; k < 16; ++k) {
      bf16x8 fa0 = *(const bf16x8*)(A0 + 16 * k);
      bf16x8 fa1 = *(const bf16x8*)(A1 + 16 * k);
      bf16x8 fb0 = *(const bf16x8*)(Bb0 + 16 * k);
      bf16x8 fb1 = *(const bf16x8*)(Bb1 + 16 * k);
      bf16x8 own = qb ? fa1 : fa0;           // row 32*wave+lrow, lk-half cols
#pragma unroll
      for (int j = 0; j < 8; ++j) rsum += (float)own[j];
      acc00 = __builtin_amdgcn_mfma_f32_32x32x16_bf16(fa0, fb0, acc00, 0, 0, 0);
      acc01 = __builtin_amdgcn_mfma_f32_32x32x16_bf16(fa0, fb1, acc01, 0, 0, 0);
      acc10 = __builtin_amdgcn_mfma_f32_32x32x16_bf16(fa1, fb0, acc10, 0, 0, 0);
      acc11 = __builtin_amdgcn_mfma_f32_32x32x16_bf16(fa1, fb1, acc11, 0, 0, 0);
    }
  }

  float rtot = rsum + __shfl_xor(rsum, 32, 64);

  if (gpart) {
    // private permuted slot: idx = wave*4096 + rr*256 + lane*4
    // -> each store instruction = 1KB contiguous. k2 un-permutes.
    float* gp = gpart + (size_t)blk * 16384 + wave * 4096;
#pragma unroll
    for (int rr = 0; rr < 16; ++rr) {
      f32x4 v;
      v[0] = acc00[rr]; v[1] = acc01[rr]; v[2] = acc10[rr]; v[3] = acc11[rr];
      *(f32x4*)(gp + rr * 256 + lane * 4) = v;
    }
    if (lk == 0) rpart[(size_t)blk * 128 + 32 * wave + lrow] = rtot;  // plain
  } else {
    float* gb = G + (size_t)b * 16384;
#pragma unroll
    for (int rr = 0; rr < 16; ++rr) {
      const int rloc = (rr & 3) + 8 * (rr >> 2) + 4 * lk;
      const int r0 = 64 * qa + rloc, r1 = 64 * qa + 32 + rloc;
      const int c0 = 64 * qb + lrow, c1 = 64 * qb + 32 + lrow;
      atomicAdd(&gb[r0 * 128 + c0], acc00[rr]);
      atomicAdd(&gb[r0 * 128 + c1], acc01[rr]);
      atomicAdd(&gb[r1 * 128 + c0], acc10[rr]);
      atomicAdd(&gb[r1 * 128 + c1], acc11[rr]);
    }
    if (lk == 0) atomicAdd(&r[b * 128 + 32 * wave + lrow], rtot);
  }
}

// ---------------------------------------------------------------------------
// K2: G[b] = sum of NCH_ permuted partials (un-permute on the L2-hot G
//     write); last 4 blocks reduce rpart -> r. Grid = 132 blocks exactly.
// ---------------------------------------------------------------------------
__global__ __launch_bounds__(256) void k2_reduce(
    const float* __restrict__ gpart, const float* __restrict__ rpart,
    float* __restrict__ G, float* __restrict__ r)
{
  const int g4 = blockIdx.x * 256 + threadIdx.x;
  if (g4 < 32768) {                                // 4 floats each
    const int b = g4 >> 12;                        // 4096 f32x4 per batch
    const int e4 = g4 & 4095;
    const f32x4* p = (const f32x4*)(gpart + ((size_t)b * NCH_) * 16384) + e4;
    f32x4 s = {0.f, 0.f, 0.f, 0.f};
#pragma unroll 8
    for (int ch = 0; ch < NCH_; ++ch) s += p[(size_t)ch * 4096];

    // un-permute: e4 = wave*1024 + rr*64 + lane
    const int w = e4 >> 10, rr = (e4 >> 6) & 15, lane = e4 & 63;
    const int lk = lane >> 5, lrow = lane & 31;
    const int qa = w >> 1, qb = w & 1;
    const int rloc = (rr & 3) + 8 * (rr >> 2) + 4 * lk;
    const int r0 = 64 * qa + rloc, c0 = 64 * qb + lrow;
    float* Gb = G + (size_t)b * 16384;
    Gb[r0 * 128 + c0]               = s[0];
    Gb[r0 * 128 + c0 + 32]          = s[1];
    Gb[(r0 + 32) * 128 + c0]        = s[2];
    Gb[(r0 + 32) * 128 + c0 + 32]   = s[3];
  } else {                                          // r reduction (1024 lanes)
    const int idx = g4 - 32768;                     // [0,1024)
    const int b = idx >> 7, d = idx & 127;
    float s = 0.f;
    for (int ch = 0; ch < NCH_; ++ch)
      s += rpart[((size_t)(b * NCH_ + ch)) * 128 + d];
    r[b * 128 + d] = s;
  }
}

// ---------------------------------------------------------------------------
// K3: per (b, c): S[c,:] = wq_c G wk'^T + exact bias terms (via r),
//     P = softmax(S/8), att_w[c,:] = P @ wv' (bf16), att_b[c] = P @ bv'
// ---------------------------------------------------------------------------
__global__ __launch_bounds__(128) void k3_softmax(
    const float* __restrict__ wq, const float* __restrict__ bq,
    const float* __restrict__ G, const float* __restrict__ r,
    const float* __restrict__ wkp, const float* __restrict__ wvp,
    const float* __restrict__ bkp, const float* __restrict__ bvp,
    bf16* __restrict__ attw, float* __restrict__ attb)
{
  const int b = blockIdx.x >> 6, c = blockIdx.x & 63;
  const int tid = threadIdx.x;
  __shared__ float sM[128], sR[128], sQ[128], sP[64];
  __shared__ float sRed;

  const float* Gb = G + (size_t)b * 16384;
  const float* wqc = wq + c * 128;

  const float rv = r[b * 128 + tid];
  sR[tid] = rv;
  float m = 0.f;
  for (int j = 0; j < 128; ++j) m += wqc[j] * Gb[j * 128 + tid];
  sM[tid] = m;
  sQ[tid] = wqc[tid] * rv;
  __syncthreads();

  if (tid < 64) {
    float q2 = sQ[tid] + sQ[tid + 64];
#pragma unroll
    for (int off = 32; off; off >>= 1) q2 += __shfl_xor(q2, off, 64);
    if (tid == 0) sRed = q2;
  }
  __syncthreads();
  const float qr = sRed;
  const float bqc = bq[c];

  if (tid < 64) {
    const int k = tid;
    float s = 0.f, wkr = 0.f;
    for (int i = 0; i < 128; ++i) {
      const float w = wkp[k * 128 + i];
      s += sM[i] * w;
      wkr += sR[i] * w;
    }
    const float bk2 = bkp[k];
    float logit = (s + bqc * wkr + bk2 * qr + (float)T_ * bqc * bk2) * 0.125f;
    float mx = logit;
#pragma unroll
    for (int off = 32; off; off >>= 1) mx = fmaxf(mx, __shfl_xor(mx, off, 64));
    const float e = __expf(logit - mx);
    float sum = e;
#pragma unroll
    for (int off = 32; off; off >>= 1) sum += __shfl_xor(sum, off, 64);
    sP[k] = e / sum;
  }
  __syncthreads();

  {
    float aw = 0.f;
    for (int k = 0; k < 64; ++k) aw += sP[k] * wvp[k * 128 + tid];
    attw[((size_t)b * 64 + c) * 128 + tid] = (bf16)aw;
  }
  if (tid < 64) {
    float pb = sP[tid] * bvp[tid];
#pragma unroll
    for (int off = 32; off; off >>= 1) pb += __shfl_xor(pb, off, 64);
    if (tid == 0) attb[b * 64 + c] = pb;
  }
}

// ---------------------------------------------------------------------------
// K4 v5: ALL global access in long contiguous chunks.
//   x staged LINEARLY into LDS in two d-halves: one instruction = one full
//   512B d-row (64 lanes x f32x2), conflict-free bf16x2 LDS writes. MFMA
//   B-frags read x from LDS (same-row u16 reads, conflict-free). Stage-2
//   and the o_s-bounced 512B-row output stores are identical to R6.
//   LDS: x_lin 16.9KB + m1 18.4KB (o_s 33.8KB aliased) -> 4 blocks/CU.
// ---------------------------------------------------------------------------
__global__ __launch_bounds__(256, 4) void k4_out(
    const float* __restrict__ x1, const float* __restrict__ mask,
    const bf16* __restrict__ wobf, const float* __restrict__ bo,
    const bf16* __restrict__ attw, const float* __restrict__ attb,
    float* __restrict__ out)
{
  __shared__ __attribute__((aligned(16))) char ubuf[35328];
  bf16*  x_lin = (bf16*)ubuf;            // [64 d-half][132 t]  16896 B
  bf16*  m1    = (bf16*)(ubuf + 16896);  // [128 t][72 c]       18432 B
  float* o_s   = (float*)ubuf;           // [64 d][132 t] epilogue (aliased)
  __shared__ float bo_s[128];
  __shared__ float ab_s[64];

  const int b = blockIdx.x >> 8;           // 256 tiles per batch
  const int t0 = (blockIdx.x & 255) << 7;
  const int tid = threadIdx.x;
  const int wave = tid >> 6, lane = tid & 63;
  const int lrow = lane & 31, lk = lane >> 5;
  const int tcol = 32 * wave + lrow;

  if (tid < 128) bo_s[tid] = bo[tid];
  if (tid < 64) ab_s[tid] = attb[b * 64 + tid];

  const float* xb = x1 + (size_t)b * D_ * T_ + t0;
  const bf16* awb = attw + (size_t)b * 8192;

  f32x16 p0 = zero16(), p1 = zero16();

#pragma unroll
  for (int dh = 0; dh < 2; ++dh) {
    // ---- stage d-half: wave w owns rows [16w,16w+16); 1 instr = 1 row
    if (dh) __syncthreads();               // part-A x_lin reads done
    const float* xs = xb + (size_t)(64 * dh + 16 * wave) * T_;
    f32x2 pr[16];
#pragma unroll
    for (int i = 0; i < 16; ++i)
      pr[i] = *(const f32x2*)(xs + (size_t)i * T_ + 2 * lane);
#pragma unroll
    for (int i = 0; i < 16; ++i) {
      bf16x2 h; h[0] = (bf16)pr[i][0]; h[1] = (bf16)pr[i][1];
      *(bf16x2*)&x_lin[(16 * wave + i) * 132 + 2 * lane] = h;
    }
    __syncthreads();

    // ---- stage-1 part: k0 covers d = 64*dh + [0,64)
#pragma unroll
    for (int k0 = 0; k0 < 4; ++k0) {
      const int kg = 4 * dh + k0;
      bf16x8 a0 = *(const bf16x8*)(awb + (size_t)lrow * 128 + 16 * kg + 8 * lk);
      bf16x8 a1 = *(const bf16x8*)(awb + (size_t)(32 + lrow) * 128 + 16 * kg + 8 * lk);
      bf16x8 bx;
#pragma unroll
      for (int j = 0; j < 8; ++j)
        bx[j] = x_lin[(16 * k0 + 8 * lk + j) * 132 + tcol];
      p0 = __builtin_amdgcn_mfma_f32_32x32x16_bf16(a0, bx, p0, 0, 0, 0);
      p1 = __builtin_amdgcn_mfma_f32_32x32x16_bf16(a1, bx, p1, 0, 0, 0);
    }
  }

  bf16* mrow = &m1[tcol * 72];              // this lane's own t-row
#pragma unroll
  for (int rr = 0; rr < 16; ++rr) {
    const int row = (rr & 3) + 8 * (rr >> 2) + 4 * lk;
    mrow[row]      = (bf16)fmaxf(p0[rr] + ab_s[row], 0.f);
    mrow[32 + row] = (bf16)fmaxf(p1[rr] + ab_s[32 + row], 0.f);
  }

  // ---- stage 2: out[d][t] = wobf[d][c] * m1[c][t] (own row, no barrier)
  f32x16 q0 = zero16(), q1 = zero16(), q2 = zero16(), q3 = zero16();
#pragma unroll
  for (int k0 = 0; k0 < 4; ++k0) {
    bf16x8 bm = *(const bf16x8*)(mrow + 16 * k0 + 8 * lk);
    bf16x8 w0 = *(const bf16x8*)(wobf + (size_t)(lrow) * 64 + 16 * k0 + 8 * lk);
    bf16x8 w1 = *(const bf16x8*)(wobf + (size_t)(32 + lrow) * 64 + 16 * k0 + 8 * lk);
    bf16x8 w2 = *(const bf16x8*)(wobf + (size_t)(64 + lrow) * 64 + 16 * k0 + 8 * lk);
    bf16x8 w3 = *(const bf16x8*)(wobf + (size_t)(96 + lrow) * 64 + 16 * k0 + 8 * lk);
    q0 = __builtin_amdgcn_mfma_f32_32x32x16_bf16(w0, bm, q0, 0, 0, 0);
    q1 = __builtin_amdgcn_mfma_f32_32x32x16_bf16(w1, bm, q1, 0, 0, 0);
    q2 = __builtin_amdgcn_mfma_f32_32x32x16_bf16(w2, bm, q2, 0, 0, 0);
    q3 = __builtin_amdgcn_mfma_f32_32x32x16_bf16(w3, bm, q3, 0, 0, 0);
  }

  // ---- epilogue: bounce through o_s so stores are full 512B row-chunks
  const float mv = mask[(size_t)b * T_ + t0 + tcol];
  float* ob = out + (size_t)b * D_ * T_ + t0;

  __syncthreads();                 // all m1/x_lin reads done before o_s
  // half 0: d in [0,64)
#pragma unroll
  for (int rr = 0; rr < 16; ++rr) {
    const int rloc = (rr & 3) + 8 * (rr >> 2) + 4 * lk;
    o_s[rloc * 132 + tcol]        = (q0[rr] + bo_s[rloc]) * mv;
    o_s[(32 + rloc) * 132 + tcol] = (q1[rr] + bo_s[32 + rloc]) * mv;
  }
  __syncthreads();
#pragma unroll
  for (int i = 0; i < 16; ++i) {
    const int dl = 16 * wave + i;
    f32x2 v = *(const f32x2*)(o_s + dl * 132 + 2 * lane);
    *(f32x2*)(ob + (size_t)dl * T_ + 2 * lane) = v;
  }
  __syncthreads();
  // half 1: d in [64,128)
#pragma unroll
  for (int rr = 0; rr < 16; ++rr) {
    const int rloc = (rr & 3) + 8 * (rr >> 2) + 4 * lk;
    o_s[rloc * 132 + tcol]        = (q2[rr] + bo_s[64 + rloc]) * mv;
    o_s[(32 + rloc) * 132 + tcol] = (q3[rr] + bo_s[96 + rloc]) * mv;
  }
  __syncthreads();
#pragma unroll
  for (int i = 0; i < 16; ++i) {
    const int dl = 16 * wave + i;
    f32x2 v = *(const f32x2*)(o_s + dl * 132 + 2 * lane);
    *(f32x2*)(ob + (size_t)(64 + dl) * T_ + 2 * lane) = v;
  }
}

// ---------------------------------------------------------------------------
// Workspace: small buffers ~0.75 MB, gpart 512*64KB = 33.5 MB, rpart 256 KB.
// Fallback to atomic path (with k0) if ws too small.
// ---------------------------------------------------------------------------
extern "C" void kernel_launch(void* const* d_in, const int* in_sizes, int n_in,
                              void* d_out, int out_size, void* d_ws, size_t ws_size,
                              hipStream_t stream)
{
  const float* x1   = (const float*)d_in[0];
  // d_in[1] = x2 (unused in encoder stage)
  const float* mask = (const float*)d_in[2];
  const float* wq   = (const float*)d_in[3];
  const float* bq   = (const float*)d_in[4];
  const float* wk   = (const float*)d_in[5];
  const float* bk   = (const float*)d_in[6];
  const float* wv   = (const float*)d_in[7];
  const float* bv   = (const float*)d_in[8];
  const float* we   = (const float*)d_in[9];
  const float* be   = (const float*)d_in[10];
  const float* wf   = (const float*)d_in[11];
  const float* bfv  = (const float*)d_in[12];
  const float* wo   = (const float*)d_in[13];
  const float* bo   = (const float*)d_in[14];
  float* out = (float*)d_out;

  char* base = (char*)d_ws;
  size_t off = 0;
  float* G    = (float*)(base + off); off += (size_t)B_ * 16384 * 4;
  float* r    = (float*)(base + off); off += (size_t)B_ * 128 * 4;
  float* wkp  = (float*)(base + off); off += 8192 * 4;
  float* wvp  = (float*)(base + off); off += 8192 * 4;
  float* bkp  = (float*)(base + off); off += 64 * 4;
  float* bvp  = (float*)(base + off); off += 64 * 4;
  float* attb = (float*)(base + off); off += (size_t)B_ * 64 * 4;
  bf16* attw  = (bf16*)(base + off);  off += (size_t)B_ * 64 * 128 * 2;
  bf16* wobf  = (bf16*)(base + off);  off += 8192 * 2;
  off = (off + 15) & ~(size_t)15;
  float* gpart = (float*)(base + off); off += (size_t)B_ * NCH_ * 16384 * 4;
  float* rpart = (float*)(base + off); off += (size_t)B_ * NCH_ * 128 * 4;
  const bool use_part = (ws_size >= off);
  if (!use_part) { gpart = nullptr; rpart = nullptr; }

  if (!use_part) {
    const int nzero = B_ * 16384 + B_ * 128;   // G + r contiguous
    k0_zero<<<(nzero + 255) / 256, 256, 0, stream>>>(G, nzero);
  }
  k1_gram<<<B_ * NCH_ + 96, 256, 0, stream>>>(
      x1, we, wk, bk, be, wf, wv, bv, bfv, wo,
      G, r, wkp, wvp, bkp, bvp, wobf, gpart, rpart);
  if (use_part)
    k2_reduce<<<132, 256, 0, stream>>>(gpart, rpart, G, r);
  k3_softmax<<<B_ * 64, 128, 0, stream>>>(wq, bq, G, r, wkp, wvp, bkp, bvp, attw, attb);
  k4_out<<<B_ * (T_ / 128), 256, 0, stream>>>(x1, mask, wobf, bo, attw, attb, out);
}